// Round 14
// baseline (180.587 us; speedup 1.0000x reference)
//
#include <hip/hip_runtime.h>
#include <hip/hip_bf16.h>
#include <hip/hip_fp16.h>

// Fused AdvancedHomeostaticCell, round 14: persistent-weight grid-stride.
// R9-R13 invariant cost: every wave re-loads its 32KB weight slice from L2
// every 64 rows. R14: 512 co-resident blocks x 8 iterations of 64 rows;
// Wi/Ws/Wf fragments loaded ONCE into registers (96 VGPR), Wo per-iter
// (hidden under pass-O MFMA); next-x prefetch overlaps pass O; 2 barriers
// per 64 rows. launch_bounds(256,2) -> 256-reg budget.

typedef __attribute__((ext_vector_type(8)))  short short8;
typedef __attribute__((ext_vector_type(16))) float f32x16;

__device__ __forceinline__ unsigned short f2bf(float f) {   // prep kernels only
    union { float f; unsigned u; } v; v.f = f;
    unsigned r = v.u + 0x7fffu + ((v.u >> 16) & 1u);
    return (unsigned short)(r >> 16);
}
__device__ __forceinline__ unsigned pk_bf16(float lo, float hi) {
    union { __hip_bfloat162 h; unsigned u; } c;
    c.h = __float22bfloat162_rn(make_float2(lo, hi));
    return c.u;
}
__device__ __forceinline__ unsigned pk_f16(float lo, float hi) {
    union { __half2 h; unsigned u; } c;
    c.h = __floats2half2_rn(lo, hi);
    return c.u;
}
__device__ __forceinline__ float lo_f16(unsigned u) {
    union { unsigned u; __half2 h; } c; c.u = u;
    return __low2float(c.h);
}
__device__ __forceinline__ float hi_f16(unsigned u) {
    union { unsigned u; __half2 h; } c; c.u = u;
    return __high2float(c.h);
}
__device__ __forceinline__ float bf2f(unsigned hs) {
    union { unsigned u; float f; } v; v.u = hs << 16;
    return v.f;
}
__device__ __forceinline__ float rcp_fast(float x) { return __builtin_amdgcn_rcpf(x); }
__device__ __forceinline__ float exp2_fast(float x) { return __builtin_amdgcn_exp2f(x); }
__device__ __forceinline__ float sigm(float x) {
    return rcp_fast(1.0f + exp2_fast(-1.4426950408889634f * x));
}
__device__ __forceinline__ float tanh_fast(float x) {
    return 1.0f - 2.0f * rcp_fast(1.0f + exp2_fast(2.8853900817779268f * x));
}
__device__ __forceinline__ f32x16 mfma_bf16(short8 a, short8 b, f32x16 c) {
    return __builtin_amdgcn_mfma_f32_32x32x16_bf16(a, b, c, 0, 0, 0);
}

#define SWZ(r) ((unsigned)(((r) & 15) << 4))
#define ITERS 8

// ---------- prep: fragment-major bf16 weights (R4/R8 layout) ---------------
// Wshuf element index = ((g*4 + jg)*8 + ks)*512 + lane*8 + e
//   g: 0=Wi, 1=Wf(x half), 2=Wslow+Wfast, 3=Wo ; jg: n-tile ; ks: k-tile
//   value[e] = Wg[jg*32 + (lane&31)][ks*16 + (lane>>5)*8 + e]
__global__ void prep_weights(const float* __restrict__ Wi_w,
                             const float* __restrict__ Wf_w,
                             const float* __restrict__ Ws_w,
                             const float* __restrict__ Wfast_w,
                             const float* __restrict__ Wo_w,
                             unsigned short* __restrict__ Wshuf) {
    int gid = blockIdx.x * 256 + threadIdx.x;   // 0 .. 65535
    int e    = gid & 7;
    int lane = (gid >> 3) & 63;
    int ks   = (gid >> 9) & 7;
    int t    = gid >> 12;                       // g*4 + jg
    int g = t >> 2, jg = t & 3;
    int row = jg * 32 + (lane & 31);
    int k   = ks * 16 + (lane >> 5) * 8 + e;
    float v;
    if (g == 0)      v = Wi_w[row * 128 + k];
    else if (g == 1) v = Wf_w[row * 256 + k];
    else if (g == 2) v = Ws_w[row * 128 + k] + Wfast_w[row * 128 + k];
    else             v = Wo_w[row * 128 + k];
    Wshuf[gid] = f2bf(v);
}

// fbias[j] = Wf_b[j] + sum_k Wf_w[j][128+k] * h_prev[k]
__global__ void prep_fbias(const float* __restrict__ Wf_w,
                           const float* __restrict__ Wf_b,
                           const float* __restrict__ hp,
                           float* __restrict__ fbias) {
    int j = threadIdx.x;
    float s = Wf_b[j];
    for (int k = 0; k < 128; ++k) s += Wf_w[j * 256 + 128 + k] * hp[k];
    fbias[j] = s;
}

// ------------------------------ main fused kernel --------------------------
__global__ __launch_bounds__(256, 2)
void cell_main(const float* __restrict__ x,
               const float* __restrict__ hp,
               const float* __restrict__ Wi_b,
               const float* __restrict__ Ws_b,
               const float* __restrict__ Wo_b,
               const float* __restrict__ ln_g,
               const float* __restrict__ ln_b,
               const unsigned short* __restrict__ Wshuf,
               const float* __restrict__ fbias,
               float* __restrict__ out) {
    const int tid  = threadIdx.x;
    const int lane = tid & 63;
    const int w    = tid >> 6;          // wave id = n-slice [32w, 32w+32)
    const int lm   = lane & 31;         // m-local (MFMA column) / weight row
    const int h    = lane >> 5;         // half-wave k-selector

    __shared__ __align__(16) char  xh[16384];        // 64 rows x 256B: x
    __shared__ __align__(16) char  hr[16384];        // 64 rows x 256B: h_raw
    __shared__ __align__(16) float prm[7 * 128];     // staged params
    __shared__ __align__(16) float red[2][4][32][2]; // [mt][w][lm][{sum,ssq}]

    const size_t blk_row0 = (size_t)blockIdx.x * (64 * ITERS);

    auto stage_x = [&](int it) {                 // coalesced f32 -> bf16 swz LDS
        const float4* xb = (const float4*)(x + (blk_row0 + (size_t)it * 64) * 128);
        #pragma unroll
        for (int i = 0; i < 8; ++i) {
            const int idx = i * 256 + tid;
            const float4 v = xb[idx];
            const int r = idx >> 5;
            const unsigned off = ((unsigned)(r * 256 + (idx & 31) * 8)) ^ SWZ(r);
            *(uint2*)(xh + off) = make_uint2(pk_bf16(v.x, v.y), pk_bf16(v.z, v.w));
        }
    };

    // ---- prologue: params, persistent weight fragments, x(0) ---------------
    {
        if (tid < 224) {                          // 7 param arrays x 128 f32
            const int a = tid >> 5, e4 = (tid & 31) * 4;
            float4 v;
            switch (a) {
                case 0: v = *(const float4*)(Wi_b + e4); break;
                case 1: v = *(const float4*)(Ws_b + e4); break;
                case 2: v = *(const float4*)(fbias + e4); break;
                case 3: v = *(const float4*)(hp + e4); break;
                case 4: v = *(const float4*)(Wo_b + e4); break;
                case 5: v = *(const float4*)(ln_g + e4); break;
                default: v = *(const float4*)(ln_b + e4); break;
            }
            *(float4*)(prm + a * 128 + e4) = v;
        }
        stage_x(0);
    }

    const unsigned short* Wl = Wshuf + (size_t)lane * 8;
    auto WFG = [&](int g, int ks) -> short8 {    // wave-contiguous 1KB load
        return *(const short8*)(const void*)(Wl + (size_t)((g * 4 + w) * 8 + ks) * 512);
    };
    short8 WiF[8], WsF[8], WfF[8];               // persistent: 96 VGPRs
    #pragma unroll
    for (int ks = 0; ks < 8; ++ks) {
        WiF[ks] = WFG(0, ks);
        WsF[ks] = WFG(2, ks);
        WfF[ks] = WFG(1, ks);
    }
    __syncthreads();                             // B1 (prologue only)

    auto LDXF = [&](int mt, int ks) -> short8 {  // x frag, row mt*32+lm
        const int r = mt * 32 + lm;
        const unsigned off = (unsigned)(r * 256) + (((unsigned)(ks * 32 + h * 16)) ^ SWZ(r));
        return *(const short8*)(xh + off);
    };
    auto LDHF = [&](int mt, int ks) -> short8 {  // h_raw frag, row mt*32+lm
        const int r = mt * 32 + lm;
        const unsigned off = (unsigned)(r * 256) + (((unsigned)(ks * 32 + h * 16)) ^ SWZ(r));
        return *(const short8*)(hr + off);
    };

    #pragma unroll 1
    for (int it = 0; it < ITERS; ++it) {
        // ---- fused ISF: one x sweep per mt, three accs, weights in regs ----
        // acc C-layout: col = lm (=m-local), n-local = j + 8q + 4h
        unsigned hpk[16];                        // h_raw bf16 pairs
        #pragma unroll
        for (int mt = 0; mt < 2; ++mt) {
            f32x16 ai, as_, af;
            #pragma unroll
            for (int e = 0; e < 16; ++e) { ai[e] = 0.f; as_[e] = 0.f; af[e] = 0.f; }
            #pragma unroll
            for (int ks = 0; ks < 8; ++ks) {
                const short8 xv = LDXF(mt, ks);
                ai  = mfma_bf16(WiF[ks], xv, ai);
                as_ = mfma_bf16(WsF[ks], xv, as_);
                af  = mfma_bf16(WfF[ks], xv, af);
            }
            #pragma unroll
            for (int q = 0; q < 4; ++q) {
                const int n0 = w * 32 + q * 8 + h * 4;
                const float4 bi  = *(const float4*)(prm + 0 * 128 + n0);
                const float4 bs  = *(const float4*)(prm + 1 * 128 + n0);
                const float4 fb4 = *(const float4*)(prm + 2 * 128 + n0);
                const float4 hp4 = *(const float4*)(prm + 3 * 128 + n0);
                const float h0 = sigm(ai[q*4+0] + bi.x) * (as_[q*4+0] + bs.x)
                               + sigm(af[q*4+0] + fb4.x) * hp4.x;
                const float h1 = sigm(ai[q*4+1] + bi.y) * (as_[q*4+1] + bs.y)
                               + sigm(af[q*4+1] + fb4.y) * hp4.y;
                const float h2 = sigm(ai[q*4+2] + bi.z) * (as_[q*4+2] + bs.z)
                               + sigm(af[q*4+2] + fb4.z) * hp4.z;
                const float h3 = sigm(ai[q*4+3] + bi.w) * (as_[q*4+3] + bs.w)
                               + sigm(af[q*4+3] + fb4.w) * hp4.w;
                hpk[mt*8+q*2+0] = pk_bf16(h0, h1);
                hpk[mt*8+q*2+1] = pk_bf16(h2, h3);
            }
            const int r = mt * 32 + lm;          // h_raw -> hr (swizzled)
            #pragma unroll
            for (int q = 0; q < 4; ++q) {
                const unsigned off = (unsigned)(r * 256)
                    + (((unsigned)((w * 32 + q * 8 + h * 4) * 2)) ^ SWZ(r));
                *(uint2*)(hr + off) = make_uint2(hpk[mt*8+q*2+0], hpk[mt*8+q*2+1]);
            }
        }
        __syncthreads();                         // B2: h_raw visible, x reads done

        // ---- prefetch next x (overlaps pass O's MFMAs) ---------------------
        if (it + 1 < ITERS) stage_x(it + 1);

        // ---- pass O: o = sigm(Wo@h_raw + bo); h_out = o*tanh(h_raw) --------
        unsigned opk[16];
        #pragma unroll
        for (int mt = 0; mt < 2; ++mt) {
            f32x16 acc;
            #pragma unroll
            for (int e = 0; e < 16; ++e) acc[e] = 0.f;
            #pragma unroll
            for (int ks = 0; ks < 8; ++ks)
                acc = mfma_bf16(WFG(3, ks), LDHF(mt, ks), acc);
            float sum = 0.f, ssq = 0.f;
            #pragma unroll
            for (int q = 0; q < 4; ++q) {
                const int n0 = w * 32 + q * 8 + h * 4;
                const float4 bo = *(const float4*)(prm + 4 * 128 + n0);
                const unsigned ha = hpk[mt*8+q*2+0], hb = hpk[mt*8+q*2+1];
                const float hv0 = sigm(acc[q*4+0] + bo.x) * tanh_fast(bf2f(ha & 0xffffu));
                const float hv1 = sigm(acc[q*4+1] + bo.y) * tanh_fast(bf2f(ha >> 16));
                const float hv2 = sigm(acc[q*4+2] + bo.z) * tanh_fast(bf2f(hb & 0xffffu));
                const float hv3 = sigm(acc[q*4+3] + bo.w) * tanh_fast(bf2f(hb >> 16));
                opk[mt*8+q*2+0] = pk_f16(hv0, hv1);
                opk[mt*8+q*2+1] = pk_f16(hv2, hv3);
                sum += hv0 + hv1 + hv2 + hv3;
                ssq += hv0*hv0 + hv1*hv1 + hv2*hv2 + hv3*hv3;
            }
            sum += __shfl_xor(sum, 32, 64);
            ssq += __shfl_xor(ssq, 32, 64);
            if (h == 0) { red[mt][w][lm][0] = sum; red[mt][w][lm][1] = ssq; }
        }
        __syncthreads();                         // B3: red + next-x visible

        // ---- in-register LN + direct store ---------------------------------
        #pragma unroll
        for (int mt = 0; mt < 2; ++mt) {
            float s = 0.f, q2 = 0.f;
            #pragma unroll
            for (int ww = 0; ww < 4; ++ww) {
                s  += red[mt][ww][lm][0];
                q2 += red[mt][ww][lm][1];
            }
            const float mean = s * (1.0f / 128.0f);
            const float var  = q2 * (1.0f / 128.0f) - mean * mean;
            const float rstd = __builtin_amdgcn_rsqf(var + 1e-5f);
            float* orow = out + (blk_row0 + (size_t)it * 64 + (size_t)(mt * 32 + lm)) * 128;
            #pragma unroll
            for (int q = 0; q < 4; ++q) {
                const int n0 = w * 32 + q * 8 + h * 4;
                const float4 g4 = *(const float4*)(prm + 5 * 128 + n0);
                const float4 b4 = *(const float4*)(prm + 6 * 128 + n0);
                const unsigned oa = opk[mt*8+q*2+0], ob = opk[mt*8+q*2+1];
                float4 rr;
                rr.x = (lo_f16(oa) - mean) * rstd * g4.x + b4.x;
                rr.y = (hi_f16(oa) - mean) * rstd * g4.y + b4.y;
                rr.z = (lo_f16(ob) - mean) * rstd * g4.z + b4.z;
                rr.w = (hi_f16(ob) - mean) * rstd * g4.w + b4.w;
                *(float4*)(orow + n0) = rr;
            }
        }
        // no loop-top barrier needed: B3 already ordered next-x writes before
        // any wave's next-iteration x reads; LN touches only red/opk/prm.
    }
}

// ------------------------------- launch ------------------------------------
extern "C" void kernel_launch(void* const* d_in, const int* in_sizes, int n_in,
                              void* d_out, int out_size, void* d_ws, size_t ws_size,
                              hipStream_t stream) {
    const float* x      = (const float*)d_in[0];
    const float* h_prev = (const float*)d_in[1];
    const float* Ws_w   = (const float*)d_in[2];
    const float* Ws_b   = (const float*)d_in[3];
    const float* Wfast  = (const float*)d_in[4];
    const float* Wi_w   = (const float*)d_in[5];
    const float* Wi_b   = (const float*)d_in[6];
    const float* Wf_w   = (const float*)d_in[7];
    const float* Wf_b   = (const float*)d_in[8];
    const float* Wo_w   = (const float*)d_in[9];
    const float* Wo_b   = (const float*)d_in[10];
    const float* ln_g   = (const float*)d_in[11];
    const float* ln_b   = (const float*)d_in[12];

    unsigned short* Wshuf = (unsigned short*)d_ws;           // 65536 bf16 = 128 KB
    float*          fb    = (float*)(Wshuf + 65536);         // 128 f32

    prep_weights<<<256, 256, 0, stream>>>(Wi_w, Wf_w, Ws_w, Wfast, Wo_w, Wshuf);
    prep_fbias<<<1, 128, 0, stream>>>(Wf_w, Wf_b, h_prev, fb);

    const int B = in_sizes[0] / 128;                         // 262144
    const int blocks = B / (64 * ITERS);                     // 512 blocks, 2/CU
    cell_main<<<blocks, 256, 0, stream>>>(x, h_prev, Wi_b, Ws_b, Wo_b,
                                          ln_g, ln_b, Wshuf, fb,
                                          (float*)d_out);
}

// Round 15
// 104.333 us; speedup vs baseline: 1.7309x; 1.7309x over previous
//
#include <hip/hip_runtime.h>
#include <hip/hip_bf16.h>
#include <hip/hip_fp16.h>

// Fused AdvancedHomeostaticCell, round 15.
// R8 (92us) is the proven best; every structural departure regressed.
// R15 = R8 with ONLY barrier reduction (5 -> 3), zero register-state change:
//  (a) h_raw in separate hr buffer -> B2/B3 merge into one barrier;
//  (b) LN stats folded into the store loop (read red directly) -> B5 gone.

typedef __attribute__((ext_vector_type(8)))  short short8;
typedef __attribute__((ext_vector_type(16))) float f32x16;

__device__ __forceinline__ unsigned short f2bf(float f) {   // prep kernels only
    union { float f; unsigned u; } v; v.f = f;
    unsigned r = v.u + 0x7fffu + ((v.u >> 16) & 1u);
    return (unsigned short)(r >> 16);
}
__device__ __forceinline__ unsigned pk_bf16(float lo, float hi) {
    union { __hip_bfloat162 h; unsigned u; } c;
    c.h = __float22bfloat162_rn(make_float2(lo, hi));
    return c.u;
}
__device__ __forceinline__ unsigned pk_f16(float lo, float hi) {
    union { __half2 h; unsigned u; } c;
    c.h = __floats2half2_rn(lo, hi);
    return c.u;
}
__device__ __forceinline__ float lo_f16(unsigned u) {
    union { unsigned u; __half2 h; } c; c.u = u;
    return __low2float(c.h);
}
__device__ __forceinline__ float hi_f16(unsigned u) {
    union { unsigned u; __half2 h; } c; c.u = u;
    return __high2float(c.h);
}
__device__ __forceinline__ float bf2f(unsigned hs) {
    union { unsigned u; float f; } v; v.u = hs << 16;
    return v.f;
}
__device__ __forceinline__ float rcp_fast(float x) { return __builtin_amdgcn_rcpf(x); }
__device__ __forceinline__ float exp2_fast(float x) { return __builtin_amdgcn_exp2f(x); }
__device__ __forceinline__ float sigm(float x) {
    return rcp_fast(1.0f + exp2_fast(-1.4426950408889634f * x));
}
__device__ __forceinline__ float tanh_fast(float x) {
    return 1.0f - 2.0f * rcp_fast(1.0f + exp2_fast(2.8853900817779268f * x));
}
__device__ __forceinline__ f32x16 mfma_bf16(short8 a, short8 b, f32x16 c) {
    return __builtin_amdgcn_mfma_f32_32x32x16_bf16(a, b, c, 0, 0, 0);
}

#define SWZ(r) ((unsigned)(((r) & 15) << 4))

// ---------- prep: fragment-major bf16 weights (R4/R8 layout) ---------------
// Wshuf element index = ((g*4 + jg)*8 + ks)*512 + lane*8 + e
//   g: 0=Wi, 1=Wf(x half), 2=Wslow+Wfast, 3=Wo ; jg: n-tile ; ks: k-tile
//   value[e] = Wg[jg*32 + (lane&31)][ks*16 + (lane>>5)*8 + e]
__global__ void prep_weights(const float* __restrict__ Wi_w,
                             const float* __restrict__ Wf_w,
                             const float* __restrict__ Ws_w,
                             const float* __restrict__ Wfast_w,
                             const float* __restrict__ Wo_w,
                             unsigned short* __restrict__ Wshuf) {
    int gid = blockIdx.x * 256 + threadIdx.x;   // 0 .. 65535
    int e    = gid & 7;
    int lane = (gid >> 3) & 63;
    int ks   = (gid >> 9) & 7;
    int t    = gid >> 12;                       // g*4 + jg
    int g = t >> 2, jg = t & 3;
    int row = jg * 32 + (lane & 31);
    int k   = ks * 16 + (lane >> 5) * 8 + e;
    float v;
    if (g == 0)      v = Wi_w[row * 128 + k];
    else if (g == 1) v = Wf_w[row * 256 + k];
    else if (g == 2) v = Ws_w[row * 128 + k] + Wfast_w[row * 128 + k];
    else             v = Wo_w[row * 128 + k];
    Wshuf[gid] = f2bf(v);
}

// fbias[j] = Wf_b[j] + sum_k Wf_w[j][128+k] * h_prev[k]
__global__ void prep_fbias(const float* __restrict__ Wf_w,
                           const float* __restrict__ Wf_b,
                           const float* __restrict__ hp,
                           float* __restrict__ fbias) {
    int j = threadIdx.x;
    float s = Wf_b[j];
    for (int k = 0; k < 128; ++k) s += Wf_w[j * 256 + 128 + k] * hp[k];
    fbias[j] = s;
}

// ------------------------------ main fused kernel --------------------------
__global__ __launch_bounds__(256, 2)
void cell_main(const float* __restrict__ x,
               const float* __restrict__ hp,
               const float* __restrict__ Wi_b,
               const float* __restrict__ Ws_b,
               const float* __restrict__ Wo_b,
               const float* __restrict__ ln_g,
               const float* __restrict__ ln_b,
               const unsigned short* __restrict__ Wshuf,
               const float* __restrict__ fbias,
               float* __restrict__ out) {
    const int tid  = threadIdx.x;
    const int lane = tid & 63;
    const int w    = tid >> 6;          // wave id = n-slice [32w, 32w+32)
    const int lm   = lane & 31;         // m-local (MFMA column) / weight row
    const int h    = lane >> 5;         // half-wave k-selector

    __shared__ __align__(16) char  xh[16384];        // 64 rows x 256B: x -> h_out
    __shared__ __align__(16) char  hr[16384];        // 64 rows x 256B: h_raw
    __shared__ __align__(16) float prm[7 * 128];     // staged params
    __shared__ __align__(16) float red[2][4][32][2]; // [mt][w][lm][{sum,ssq}]

    const size_t row0 = (size_t)blockIdx.x * 64;

    // ---- stage x (coalesced f32 -> bf16 swizzled) + params -----------------
    {
        const float4* xb = (const float4*)(x + row0 * 128);  // 2048 float4
        #pragma unroll
        for (int it = 0; it < 8; ++it) {
            const int idx = it * 256 + tid;
            const float4 v = xb[idx];
            const int r = idx >> 5;
            const unsigned off = ((unsigned)(r * 256 + (idx & 31) * 8)) ^ SWZ(r);
            *(uint2*)(xh + off) = make_uint2(pk_bf16(v.x, v.y), pk_bf16(v.z, v.w));
        }
        if (tid < 224) {                          // 7 param arrays x 128 f32
            const int a = tid >> 5, e4 = (tid & 31) * 4;
            float4 v;
            switch (a) {
                case 0: v = *(const float4*)(Wi_b + e4); break;
                case 1: v = *(const float4*)(Ws_b + e4); break;
                case 2: v = *(const float4*)(fbias + e4); break;
                case 3: v = *(const float4*)(hp + e4); break;
                case 4: v = *(const float4*)(Wo_b + e4); break;
                case 5: v = *(const float4*)(ln_g + e4); break;
                default: v = *(const float4*)(ln_b + e4); break;
            }
            *(float4*)(prm + a * 128 + e4) = v;
        }
    }
    __syncthreads();                              // B1

    auto LDXF = [&](int mt, int ks) -> short8 {   // x frag, row mt*32+lm
        const int r = mt * 32 + lm;
        const unsigned off = (unsigned)(r * 256) + (((unsigned)(ks * 32 + h * 16)) ^ SWZ(r));
        return *(const short8*)(xh + off);
    };
    auto LDHF = [&](int mt, int ks) -> short8 {   // h_raw frag, row mt*32+lm
        const int r = mt * 32 + lm;
        const unsigned off = (unsigned)(r * 256) + (((unsigned)(ks * 32 + h * 16)) ^ SWZ(r));
        return *(const short8*)(hr + off);
    };
    // direct fragment-major weight load: wave-contiguous 1KB, L2-resident
    const unsigned short* Wl = Wshuf + (size_t)lane * 8;
    auto WFG = [&](int g, int ks) -> short8 {
        return *(const short8*)(const void*)(Wl + (size_t)((g * 4 + w) * 8 + ks) * 512);
    };

    // ---- pass I: ik = sigm(Wi@x + bi) (f16 pairs) --------------------------
    // acc C-layout: col = lm (=m-local), n-local = j + 8q + 4h
    unsigned ik[16];
    #pragma unroll
    for (int mt = 0; mt < 2; ++mt) {
        f32x16 acc;
        #pragma unroll
        for (int e = 0; e < 16; ++e) acc[e] = 0.f;
        #pragma unroll
        for (int ks = 0; ks < 8; ++ks)
            acc = mfma_bf16(WFG(0, ks), LDXF(mt, ks), acc);
        #pragma unroll
        for (int q = 0; q < 4; ++q) {
            const int n0 = w * 32 + q * 8 + h * 4;
            const float4 bi = *(const float4*)(prm + 0 * 128 + n0);
            ik[mt*8+q*2+0] = pk_f16(sigm(acc[q*4+0] + bi.x), sigm(acc[q*4+1] + bi.y));
            ik[mt*8+q*2+1] = pk_f16(sigm(acc[q*4+2] + bi.z), sigm(acc[q*4+3] + bi.w));
        }
    }

    // ---- pass S: ppk = ik * (Ws@x + bs) (f16 pairs) ------------------------
    unsigned ppk[16];
    #pragma unroll
    for (int mt = 0; mt < 2; ++mt) {
        f32x16 acc;
        #pragma unroll
        for (int e = 0; e < 16; ++e) acc[e] = 0.f;
        #pragma unroll
        for (int ks = 0; ks < 8; ++ks)
            acc = mfma_bf16(WFG(2, ks), LDXF(mt, ks), acc);
        #pragma unroll
        for (int q = 0; q < 4; ++q) {
            const int n0 = w * 32 + q * 8 + h * 4;
            const float4 bs = *(const float4*)(prm + 1 * 128 + n0);
            const unsigned ia = ik[mt*8+q*2+0], ib = ik[mt*8+q*2+1];
            ppk[mt*8+q*2+0] = pk_f16(lo_f16(ia) * (acc[q*4+0] + bs.x),
                                     hi_f16(ia) * (acc[q*4+1] + bs.y));
            ppk[mt*8+q*2+1] = pk_f16(lo_f16(ib) * (acc[q*4+2] + bs.z),
                                     hi_f16(ib) * (acc[q*4+3] + bs.w));
        }
    }

    // ---- pass F: hpk = ppk + sigm(Wf@x + fb) * hp; write h_raw -> hr -------
    unsigned hpk[16];
    #pragma unroll
    for (int mt = 0; mt < 2; ++mt) {
        f32x16 acc;
        #pragma unroll
        for (int e = 0; e < 16; ++e) acc[e] = 0.f;
        #pragma unroll
        for (int ks = 0; ks < 8; ++ks)
            acc = mfma_bf16(WFG(1, ks), LDXF(mt, ks), acc);
        #pragma unroll
        for (int q = 0; q < 4; ++q) {
            const int n0 = w * 32 + q * 8 + h * 4;
            const float4 fb4 = *(const float4*)(prm + 2 * 128 + n0);
            const float4 hp4 = *(const float4*)(prm + 3 * 128 + n0);
            const unsigned pa = ppk[mt*8+q*2+0], pb = ppk[mt*8+q*2+1];
            hpk[mt*8+q*2+0] = pk_bf16(lo_f16(pa) + sigm(acc[q*4+0] + fb4.x) * hp4.x,
                                      hi_f16(pa) + sigm(acc[q*4+1] + fb4.y) * hp4.y);
            hpk[mt*8+q*2+1] = pk_bf16(lo_f16(pb) + sigm(acc[q*4+2] + fb4.z) * hp4.z,
                                      hi_f16(pb) + sigm(acc[q*4+3] + fb4.w) * hp4.w);
        }
        const int r = mt * 32 + lm;               // h_raw -> hr (swizzled)
        #pragma unroll
        for (int q = 0; q < 4; ++q) {
            const unsigned off = (unsigned)(r * 256)
                + (((unsigned)((w * 32 + q * 8 + h * 4) * 2)) ^ SWZ(r));
            *(uint2*)(hr + off) = make_uint2(hpk[mt*8+q*2+0], hpk[mt*8+q*2+1]);
        }
    }
    __syncthreads();                              // B2: h_raw visible, x reads done

    // ---- pass O: o = sigm(Wo@h_raw + bo); h_out = o*tanh(h_raw) ------------
    unsigned opk[16];
    #pragma unroll
    for (int mt = 0; mt < 2; ++mt) {
        f32x16 acc;
        #pragma unroll
        for (int e = 0; e < 16; ++e) acc[e] = 0.f;
        #pragma unroll
        for (int ks = 0; ks < 8; ++ks)
            acc = mfma_bf16(WFG(3, ks), LDHF(mt, ks), acc);
        float sum = 0.f, ssq = 0.f;
        #pragma unroll
        for (int q = 0; q < 4; ++q) {
            const int n0 = w * 32 + q * 8 + h * 4;
            const float4 bo = *(const float4*)(prm + 4 * 128 + n0);
            const unsigned ha = hpk[mt*8+q*2+0], hb = hpk[mt*8+q*2+1];
            const float hv0 = sigm(acc[q*4+0] + bo.x) * tanh_fast(bf2f(ha & 0xffffu));
            const float hv1 = sigm(acc[q*4+1] + bo.y) * tanh_fast(bf2f(ha >> 16));
            const float hv2 = sigm(acc[q*4+2] + bo.z) * tanh_fast(bf2f(hb & 0xffffu));
            const float hv3 = sigm(acc[q*4+3] + bo.w) * tanh_fast(bf2f(hb >> 16));
            opk[mt*8+q*2+0] = pk_f16(hv0, hv1);
            opk[mt*8+q*2+1] = pk_f16(hv2, hv3);
            sum += hv0 + hv1 + hv2 + hv3;
            ssq += hv0*hv0 + hv1*hv1 + hv2*hv2 + hv3*hv3;
        }
        sum += __shfl_xor(sum, 32, 64);
        ssq += __shfl_xor(ssq, 32, 64);
        if (h == 0) { red[mt][w][lm][0] = sum; red[mt][w][lm][1] = ssq; }
    }

    // ---- h_out -> xh (legal: all x reads finished at B2) -------------------
    #pragma unroll
    for (int mt = 0; mt < 2; ++mt) {
        const int r = mt * 32 + lm;
        #pragma unroll
        for (int q = 0; q < 4; ++q) {
            const unsigned off = (unsigned)(r * 256)
                + (((unsigned)((w * 32 + q * 8 + h * 4) * 2)) ^ SWZ(r));
            *(uint2*)(xh + off) = make_uint2(opk[mt*8+q*2+0], opk[mt*8+q*2+1]);
        }
    }
    __syncthreads();                              // B3: h_out + red visible

    // ---- LN (stats inline from red) + fully coalesced store ----------------
    float* ob = out + row0 * 128;
    #pragma unroll
    for (int it = 0; it < 8; ++it) {
        const int idx = it * 256 + tid;           // float4 index, coalesced
        const int r = idx >> 5;
        const int mt = r >> 5, l = r & 31;
        const int c4 = (idx & 31) * 4;            // feature col base
        float s = 0.f, q2 = 0.f;
        #pragma unroll
        for (int ww = 0; ww < 4; ++ww) {
            const float2 p = *(const float2*)&red[mt][ww][l][0];
            s += p.x; q2 += p.y;
        }
        const float mean = s * (1.0f / 128.0f);
        const float var  = q2 * (1.0f / 128.0f) - mean * mean;
        const float rstd = __builtin_amdgcn_rsqf(var + 1e-5f);
        const unsigned off = (unsigned)(r * 256) + (((unsigned)(c4 * 2)) ^ SWZ(r));
        const uint2 hv = *(const uint2*)(xh + off);
        const float4 g4 = *(const float4*)(prm + 5 * 128 + c4);
        const float4 b4 = *(const float4*)(prm + 6 * 128 + c4);
        float4 rr;
        rr.x = (lo_f16(hv.x) - mean) * rstd * g4.x + b4.x;
        rr.y = (hi_f16(hv.x) - mean) * rstd * g4.y + b4.y;
        rr.z = (lo_f16(hv.y) - mean) * rstd * g4.z + b4.z;
        rr.w = (hi_f16(hv.y) - mean) * rstd * g4.w + b4.w;
        *(float4*)(ob + (size_t)idx * 4) = rr;
    }
}

// ------------------------------- launch ------------------------------------
extern "C" void kernel_launch(void* const* d_in, const int* in_sizes, int n_in,
                              void* d_out, int out_size, void* d_ws, size_t ws_size,
                              hipStream_t stream) {
    const float* x      = (const float*)d_in[0];
    const float* h_prev = (const float*)d_in[1];
    const float* Ws_w   = (const float*)d_in[2];
    const float* Ws_b   = (const float*)d_in[3];
    const float* Wfast  = (const float*)d_in[4];
    const float* Wi_w   = (const float*)d_in[5];
    const float* Wi_b   = (const float*)d_in[6];
    const float* Wf_w   = (const float*)d_in[7];
    const float* Wf_b   = (const float*)d_in[8];
    const float* Wo_w   = (const float*)d_in[9];
    const float* Wo_b   = (const float*)d_in[10];
    const float* ln_g   = (const float*)d_in[11];
    const float* ln_b   = (const float*)d_in[12];

    unsigned short* Wshuf = (unsigned short*)d_ws;           // 65536 bf16 = 128 KB
    float*          fb    = (float*)(Wshuf + 65536);         // 128 f32

    prep_weights<<<256, 256, 0, stream>>>(Wi_w, Wf_w, Ws_w, Wfast, Wo_w, Wshuf);
    prep_fbias<<<1, 128, 0, stream>>>(Wf_w, Wf_b, h_prev, fb);

    const int B = in_sizes[0] / 128;                         // 262144
    const int blocks = B / 64;                               // 64 rows per block
    cell_main<<<blocks, 256, 0, stream>>>(x, h_prev, Wi_b, Ws_b, Wo_b,
                                          ln_g, ln_b, Wshuf, fb,
                                          (float*)d_out);
}